// Round 9
// baseline (52.146 us; speedup 1.0000x reference)
//
#include <hip/hip_runtime.h>
#include <stdint.h>

#define OUT_ROIS 128
#define FG_MAX 32
#define BG_PID_F 5532.0f
#define MAXCH 2304            // max 64-roi chunks supported (N <= 147456)
#define CLS_REPS 2            // MEASUREMENT: run j-loop twice (idempotent max-accum)

// Exact f32 threshold discriminants (no division, no f64):
//  FG: RN32(I/D) >= 0.5f  <=>  I - (0.5-2^-26)*D >= 0   [tie->even lands on 0.5f: inclusive]
//  BG: RN32(I/D) >= 0.1f  <=>  I - (0.1f-2^-28)*D > 0   [tie->even lands on pred(0.1f): strict]

// ---------------- Kernel 1: per-roi fg/bg classification ----------------
__global__ __launch_bounds__(256, 4) void ptl_classify(
    const float* __restrict__ all_rois, const float* __restrict__ gt,
    int R, int G, int N,
    uint8_t* __restrict__ code, int* __restrict__ blkF, int* __restrict__ blkB)
{
#pragma clang fp contract(off)
    __shared__ float4 g4[256];
    __shared__ float  gA[256];
    __shared__ uint8_t flg[4][128];
    const int t = threadIdx.x;
    const int w = t >> 6, lane = t & 63;

    if (t < G) {
        const float* p = gt + (size_t)t * 6;
        const float a = p[0], b = p[1], c = p[2], d = p[3];
        g4[t] = make_float4(a, b, c, d);
        gA[t] = ((c - a) + 1.0f) * ((d - b) + 1.0f);   // reference expr tree
    }
    __syncthreads();

    const int base = blockIdx.x * 128;
    float x1a, y1a, x2a, y2a, x1b, y1b, x2b, y2b;
    {
        const int i0 = base + lane;
        if (i0 < N) {
            if (i0 < R) { const float* p = all_rois + (size_t)i0 * 5; x1a=p[1]; y1a=p[2]; x2a=p[3]; y2a=p[4]; }
            else        { const float* p = gt + (size_t)(i0 - R) * 6; x1a=p[0]; y1a=p[1]; x2a=p[2]; y2a=p[3]; }
        } else { x1a=0.0f; y1a=0.0f; x2a=-2.0f; y2a=-2.0f; }
        const int i1 = base + 64 + lane;
        if (i1 < N) {
            if (i1 < R) { const float* p = all_rois + (size_t)i1 * 5; x1b=p[1]; y1b=p[2]; x2b=p[3]; y2b=p[4]; }
            else        { const float* p = gt + (size_t)(i1 - R) * 6; x1b=p[0]; y1b=p[1]; x2b=p[2]; y2b=p[3]; }
        } else { x1b=0.0f; y1b=0.0f; x2b=-2.0f; y2b=-2.0f; }
    }
    const float Aa = ((x2a - x1a) + 1.0f) * ((y2a - y1a) + 1.0f);
    const float Ab = ((x2b - x1b) + 1.0f) * ((y2b - y1b) + 1.0f);

    float aF0 = -1e38f, aB0 = -1e38f, aF1 = -1e38f, aB1 = -1e38f;

#define IOU2(QQ, GAv)                                                   \
    do {                                                                \
        const float4 q_ = (QQ); const float ga_ = (GAv);                \
        {   float iw = (fminf(x2a, q_.z) - fmaxf(x1a, q_.x)) + 1.0f;    \
            float ih = (fminf(y2a, q_.w) - fmaxf(y1a, q_.y)) + 1.0f;    \
            iw = fmaxf(iw, 0.0f); ih = fmaxf(ih, 0.0f);                 \
            const float I = iw * ih;                                    \
            const float D = (Aa + ga_) - I;                             \
            const float h  = fmaf(-0.5f, D, I);                         \
            const float gF = fmaf(0x1p-26f, D, h);                      \
            const float h2 = fmaf(-0.1f, D, I);                         \
            const float gB = fmaf(0x1p-28f, D, h2);                     \
            aF0 = fmaxf(aF0, gF); aB0 = fmaxf(aB0, gB); }               \
        {   float iw = (fminf(x2b, q_.z) - fmaxf(x1b, q_.x)) + 1.0f;    \
            float ih = (fminf(y2b, q_.w) - fmaxf(y1b, q_.y)) + 1.0f;    \
            iw = fmaxf(iw, 0.0f); ih = fmaxf(ih, 0.0f);                 \
            const float I = iw * ih;                                    \
            const float D = (Ab + ga_) - I;                             \
            const float h  = fmaf(-0.5f, D, I);                         \
            const float gF = fmaf(0x1p-26f, D, h);                      \
            const float h2 = fmaf(-0.1f, D, I);                         \
            const float gB = fmaf(0x1p-28f, D, h2);                     \
            aF1 = fmaxf(aF1, gF); aB1 = fmaxf(aB1, gB); }               \
    } while (0)

    for (int rep = 0; rep < CLS_REPS; ++rep) {        // idempotent re-accumulation
        if (G == 256) {
            const int jbeg = w * 64;
            float4 qb0[8], qb1[8];
            float  ga0[8], ga1[8];
#pragma unroll
            for (int uu = 0; uu < 8; ++uu) { qb0[uu] = g4[jbeg + uu]; ga0[uu] = gA[jbeg + uu]; }
#pragma unroll
            for (int grp = 0; grp < 8; ++grp) {
                if ((grp & 1) == 0) {
                    if (grp + 1 < 8) {
#pragma unroll
                        for (int uu = 0; uu < 8; ++uu) {
                            qb1[uu] = g4[jbeg + (grp + 1) * 8 + uu];
                            ga1[uu] = gA[jbeg + (grp + 1) * 8 + uu];
                        }
                    }
#pragma unroll
                    for (int uu = 0; uu < 8; ++uu) IOU2(qb0[uu], ga0[uu]);
                } else {
                    if (grp + 1 < 8) {
#pragma unroll
                        for (int uu = 0; uu < 8; ++uu) {
                            qb0[uu] = g4[jbeg + (grp + 1) * 8 + uu];
                            ga0[uu] = gA[jbeg + (grp + 1) * 8 + uu];
                        }
                    }
#pragma unroll
                    for (int uu = 0; uu < 8; ++uu) IOU2(qb1[uu], ga1[uu]);
                }
            }
        } else {
            const int jbeg = (G * w) >> 2, jend = (G * (w + 1)) >> 2;
            for (int j = jbeg; j < jend; ++j) IOU2(g4[j], gA[j]);
        }
    }
#undef IOU2

    flg[w][lane]      = (uint8_t)((aF0 >= 0.0f ? 1u : 0u) | (aB0 > 0.0f ? 2u : 0u));
    flg[w][64 + lane] = (uint8_t)((aF1 >= 0.0f ? 1u : 0u) | (aB1 > 0.0f ? 2u : 0u));
    __syncthreads();

    if (t < 128) {
        const uint32_t u = (uint32_t)flg[0][t] | flg[1][t] | flg[2][t] | flg[3][t];
        const int cls = (u & 1u) ? 1 : ((u & 2u) ? 2 : 0);
        const int i2 = base + t;
        if (i2 < N) code[i2] = (uint8_t)cls;
        unsigned long long mF = __ballot(cls == 1);
        unsigned long long mB = __ballot(cls == 2);
        if ((t & 63) == 0) {
            blkF[blockIdx.x * 2 + (t >> 6)] = __popcll(mF);
            blkB[blockIdx.x * 2 + (t >> 6)] = __popcll(mB);
        }
    }
}

// ---------------- Kernel 2: ordered first-k selection + fg argmax + epilogue ----
__global__ __launch_bounds__(256) void ptl_select_emit(
    const float* __restrict__ all_rois, const float* __restrict__ gt,
    const uint8_t* __restrict__ code,
    const int* __restrict__ blkF, const int* __restrict__ blkB,
    int R, int G, int N, int nch,
    float* __restrict__ out)
{
#pragma clang fp contract(off)
    __shared__ int sF[MAXCH], sB[MAXCH];
    __shared__ int EF[MAXCH], EB[MAXCH];
    __shared__ int tsF[256], tsB[256];
    __shared__ int keep[OUT_ROIS];
    __shared__ int sam[OUT_ROIS];
    __shared__ int nwork;
    __shared__ unsigned short work[MAXCH];
    const int t = threadIdx.x;

    for (int c = t; c < nch; c += 256) { sF[c] = blkF[c]; sB[c] = blkB[c]; }
    for (int c = nch + t; c < MAXCH; c += 256) { sF[c] = 0; sB[c] = 0; }
    if (t < OUT_ROIS) { keep[t] = 0; sam[t] = 0; }   // unfilled slots -> roi 0
    if (t == 0) nwork = 0;
    __syncthreads();

    const int c0 = t * (MAXCH / 256);
    int baseF = 0, baseB = 0;
#pragma unroll
    for (int k = 0; k < MAXCH / 256; ++k) { baseF += sF[c0 + k]; baseB += sB[c0 + k]; }
    tsF[t] = baseF; tsB[t] = baseB;
    __syncthreads();
    for (int d = 1; d < 256; d <<= 1) {
        int vF = (t >= d) ? tsF[t - d] : 0;
        int vB = (t >= d) ? tsB[t - d] : 0;
        __syncthreads();
        tsF[t] += vF; tsB[t] += vB;
        __syncthreads();
    }
    const int tf = tsF[255], tb = tsB[255];
    const int num_fg = tf < FG_MAX ? tf : FG_MAX;
    const int rem = OUT_ROIS - num_fg;
    const int num_bg = tb < rem ? tb : rem;

    int rF = tsF[t] - baseF, rB = tsB[t] - baseB;
#pragma unroll
    for (int k = 0; k < MAXCH / 256; ++k) {
        const int c = c0 + k;
        const int cf = sF[c], cb = sB[c];
        EF[c] = rF; EB[c] = rB;
        const bool need = ((cf > 0 && rF < num_fg) || (cb > 0 && rB < num_bg)) && (c < nch);
        if (need) { int p = atomicAdd(&nwork, 1); work[p] = (unsigned short)c; }
        rF += cf; rB += cb;
    }
    __syncthreads();

    const int w = t >> 6, lane = t & 63;
    const unsigned long long lowmask = (1ull << lane) - 1ull;
    const int nw = nwork;
    for (int idx = w; idx < nw; idx += 4) {
        const int c = work[idx];
        const int i = c * 64 + lane;
        const int cd = (i < N) ? (int)code[i] : 0;
        unsigned long long mF = __ballot(cd == 1);
        unsigned long long mB = __ballot(cd == 2);
        const int pF = EF[c] + __popcll(mF & lowmask);
        const int pB = EB[c] + __popcll(mB & lowmask);
        if (cd == 1 && pF < num_fg) keep[pF] = i;
        if (cd == 2 && pB < num_bg) keep[num_fg + pB] = i;
    }
    __syncthreads();

    // fg argmax: one wave per fg slot, lane-parallel over gt, IEEE f32 div.
    for (int s = w; s < num_fg; s += 4) {
        const int k = keep[s];
        float x1, y1, x2, y2;
        if (k < R) { const float* p = all_rois + (size_t)k * 5; x1=p[1]; y1=p[2]; x2=p[3]; y2=p[4]; }
        else       { const float* p = gt + (size_t)(k - R) * 6; x1=p[0]; y1=p[1]; x2=p[2]; y2=p[3]; }
        const float A = ((x2 - x1) + 1.0f) * ((y2 - y1) + 1.0f);
        float mv = -1.0f; int mj = 0;
        for (int jj = 0; jj < 4; ++jj) {
            const int j = jj * 64 + lane;
            float iou = -1.0f;
            if (j < G) {
                const float* p = gt + (size_t)j * 6;
                const float a = p[0], b = p[1], c2 = p[2], d2 = p[3];
                const float ga = ((c2 - a) + 1.0f) * ((d2 - b) + 1.0f);
                float iw = (fminf(x2, c2) - fmaxf(x1, a)) + 1.0f;
                float ih = (fminf(y2, d2) - fmaxf(y1, b)) + 1.0f;
                iw = fmaxf(iw, 0.0f); ih = fmaxf(ih, 0.0f);
                const float inter = iw * ih;
                iou = inter / ((A + ga) - inter);   // IEEE, matches numpy
            }
            if (iou > mv) { mv = iou; mj = j; }
        }
#pragma unroll
        for (int m = 1; m < 64; m <<= 1) {
            const float ov = __shfl_xor(mv, m);
            const int oj = __shfl_xor(mj, m);
            if (ov > mv || (ov == mv && oj < mj)) { mv = ov; mj = oj; }
        }
        if (lane == 0) sam[s] = mj;
    }
    __syncthreads();

    if (t < OUT_ROIS) {
        const int s = t;
        const int k = keep[s];
        const bool isfg = s < num_fg;
        float x1, y1, x2, y2;
        if (k < R) { const float* p = all_rois + (size_t)k * 5; x1=p[1]; y1=p[2]; x2=p[3]; y2=p[4]; }
        else       { const float* p = gt + (size_t)(k - R) * 6; x1=p[0]; y1=p[1]; x2=p[2]; y2=p[3]; }
        const int amax = sam[s];
        const float* g = gt + (size_t)amax * 6;
        const float gx1v = g[0], gy1v = g[1], gx2v = g[2], gy2v = g[3];
        const float label = isfg ? g[4] : 0.0f;
        const float pid = isfg ? g[5] : BG_PID_F;

        float* ro = out + (size_t)s * 5;
        ro[0] = 0.0f; ro[1] = x1; ro[2] = y1; ro[3] = x2; ro[4] = y2;
        out[640 + s] = (float)(int)label;
        out[768 + s] = (float)(int)pid;

        const float ew = (x2 - x1) + 1.0f, eh = (y2 - y1) + 1.0f;
        const float ecx = x1 + 0.5f * ew, ecy = y1 + 0.5f * eh;
        const float gw = (gx2v - gx1v) + 1.0f, gh = (gy2v - gy1v) + 1.0f;
        const float gcx = gx1v + 0.5f * gw, gcy = gy1v + 0.5f * gh;
        float tv[4];
        tv[0] = ((gcx - ecx) / ew) / 0.1f;
        tv[1] = ((gcy - ecy) / eh) / 0.1f;
        tv[2] = logf(gw / ew) / 0.2f;
        tv[3] = logf(gh / eh) / 0.2f;

        const int cls = (int)roundf(label);
        const float on = (label > 0.0f) ? 1.0f : 0.0f;

        float* bt = out + 896  + (size_t)s * 8;
        float* bi = out + 1920 + (size_t)s * 8;
        float* bo = out + 2944 + (size_t)s * 8;
#pragma unroll
        for (int cc = 0; cc < 2; ++cc) {
            const float sel = (cc == cls) ? on : 0.0f;
#pragma unroll
            for (int j = 0; j < 4; ++j) {
                bt[cc * 4 + j] = sel * tv[j];
                bi[cc * 4 + j] = sel;
                bo[cc * 4 + j] = sel;
            }
        }
    }
}

extern "C" void kernel_launch(void* const* d_in, const int* in_sizes, int n_in,
                              void* d_out, int out_size, void* d_ws, size_t ws_size,
                              hipStream_t stream) {
    const float* all_rois = (const float*)d_in[0];
    const float* gt       = (const float*)d_in[1];
    const int R = in_sizes[0] / 5;
    const int G = in_sizes[1] / 6;
    const int N = R + G;
    const int nblk = (N + 127) / 128;  // classify tiles (128 rois each)
    const int nch = (N + 63) / 64;     // 64-roi chunks for selection

    uint8_t* code = (uint8_t*)d_ws;
    size_t codeBytes = ((size_t)N + 255) & ~(size_t)255;
    int* blkF = (int*)((char*)d_ws + codeBytes);
    int* blkB = blkF + 2 * nblk;
    float* out = (float*)d_out;

    ptl_classify<<<nblk, 256, 0, stream>>>(all_rois, gt, R, G, N, code, blkF, blkB);
    ptl_select_emit<<<1, 256, 0, stream>>>(all_rois, gt, code, blkF, blkB, R, G, N, nch, out);
}

// Round 10
// 38.739 us; speedup vs baseline: 1.3461x; 1.3461x over previous
//
#include <hip/hip_runtime.h>
#include <stdint.h>

#define OUT_ROIS 128
#define FG_MAX 32
#define BG_PID_F 5532.0f
#define MAXCH 2304            // max 64-roi chunks supported (N <= 147456)

// Exact f32 threshold discriminants (no division, no f64):
//  FG: RN32(I/D) >= 0.5f  <=>  I - (0.5-2^-26)*D >= 0   [tie->even lands on 0.5f: inclusive]
//  BG: RN32(I/D) >= 0.1f  <=>  I - (0.1f-2^-28)*D > 0   [tie->even lands on pred(0.1f): strict]

// ---------------- Kernel 1: per-roi fg/bg classification ----------------
// Proven bit-exact hot loop (R6/R7). Output: per-64-chunk fg/bg ballot masks
// as ulonglong2{mF,mB} -- one 16B store per chunk, no code[]/count arrays.
__global__ __launch_bounds__(256, 4) void ptl_classify(
    const float* __restrict__ all_rois, const float* __restrict__ gt,
    int R, int G, int N,
    ulonglong2* __restrict__ mb2)
{
#pragma clang fp contract(off)
    __shared__ float4 g4[256];
    __shared__ float  gA[256];
    __shared__ uint8_t flg[4][128];
    const int t = threadIdx.x;
    const int w = t >> 6, lane = t & 63;

    if (t < G) {
        const float* p = gt + (size_t)t * 6;
        const float a = p[0], b = p[1], c = p[2], d = p[3];
        g4[t] = make_float4(a, b, c, d);
        gA[t] = ((c - a) + 1.0f) * ((d - b) + 1.0f);   // reference expr tree
    }
    __syncthreads();

    const int base = blockIdx.x * 128;
    float x1a, y1a, x2a, y2a, x1b, y1b, x2b, y2b;
    {
        const int i0 = base + lane;
        if (i0 < N) {
            if (i0 < R) { const float* p = all_rois + (size_t)i0 * 5; x1a=p[1]; y1a=p[2]; x2a=p[3]; y2a=p[4]; }
            else        { const float* p = gt + (size_t)(i0 - R) * 6; x1a=p[0]; y1a=p[1]; x2a=p[2]; y2a=p[3]; }
        } else { x1a=0.0f; y1a=0.0f; x2a=-2.0f; y2a=-2.0f; }
        const int i1 = base + 64 + lane;
        if (i1 < N) {
            if (i1 < R) { const float* p = all_rois + (size_t)i1 * 5; x1b=p[1]; y1b=p[2]; x2b=p[3]; y2b=p[4]; }
            else        { const float* p = gt + (size_t)(i1 - R) * 6; x1b=p[0]; y1b=p[1]; x2b=p[2]; y2b=p[3]; }
        } else { x1b=0.0f; y1b=0.0f; x2b=-2.0f; y2b=-2.0f; }
    }
    const float Aa = ((x2a - x1a) + 1.0f) * ((y2a - y1a) + 1.0f);
    const float Ab = ((x2b - x1b) + 1.0f) * ((y2b - y1b) + 1.0f);

    float aF0 = -1e38f, aB0 = -1e38f, aF1 = -1e38f, aB1 = -1e38f;

#define IOU2(QQ, GAv)                                                   \
    do {                                                                \
        const float4 q_ = (QQ); const float ga_ = (GAv);                \
        {   float iw = (fminf(x2a, q_.z) - fmaxf(x1a, q_.x)) + 1.0f;    \
            float ih = (fminf(y2a, q_.w) - fmaxf(y1a, q_.y)) + 1.0f;    \
            iw = fmaxf(iw, 0.0f); ih = fmaxf(ih, 0.0f);                 \
            const float I = iw * ih;                                    \
            const float D = (Aa + ga_) - I;                             \
            const float h  = fmaf(-0.5f, D, I);                         \
            const float gF = fmaf(0x1p-26f, D, h);                      \
            const float h2 = fmaf(-0.1f, D, I);                         \
            const float gB = fmaf(0x1p-28f, D, h2);                     \
            aF0 = fmaxf(aF0, gF); aB0 = fmaxf(aB0, gB); }               \
        {   float iw = (fminf(x2b, q_.z) - fmaxf(x1b, q_.x)) + 1.0f;    \
            float ih = (fminf(y2b, q_.w) - fmaxf(y1b, q_.y)) + 1.0f;    \
            iw = fmaxf(iw, 0.0f); ih = fmaxf(ih, 0.0f);                 \
            const float I = iw * ih;                                    \
            const float D = (Ab + ga_) - I;                             \
            const float h  = fmaf(-0.5f, D, I);                         \
            const float gF = fmaf(0x1p-26f, D, h);                      \
            const float h2 = fmaf(-0.1f, D, I);                         \
            const float gB = fmaf(0x1p-28f, D, h2);                     \
            aF1 = fmaxf(aF1, gF); aB1 = fmaxf(aB1, gB); }               \
    } while (0)

    if (G == 256) {
        const int jbeg = w * 64;
        float4 qb0[8], qb1[8];
        float  ga0[8], ga1[8];
#pragma unroll
        for (int uu = 0; uu < 8; ++uu) { qb0[uu] = g4[jbeg + uu]; ga0[uu] = gA[jbeg + uu]; }
#pragma unroll
        for (int grp = 0; grp < 8; ++grp) {
            if ((grp & 1) == 0) {
                if (grp + 1 < 8) {
#pragma unroll
                    for (int uu = 0; uu < 8; ++uu) {
                        qb1[uu] = g4[jbeg + (grp + 1) * 8 + uu];
                        ga1[uu] = gA[jbeg + (grp + 1) * 8 + uu];
                    }
                }
#pragma unroll
                for (int uu = 0; uu < 8; ++uu) IOU2(qb0[uu], ga0[uu]);
            } else {
                if (grp + 1 < 8) {
#pragma unroll
                    for (int uu = 0; uu < 8; ++uu) {
                        qb0[uu] = g4[jbeg + (grp + 1) * 8 + uu];
                        ga0[uu] = gA[jbeg + (grp + 1) * 8 + uu];
                    }
                }
#pragma unroll
                for (int uu = 0; uu < 8; ++uu) IOU2(qb1[uu], ga1[uu]);
            }
        }
    } else {
        const int jbeg = (G * w) >> 2, jend = (G * (w + 1)) >> 2;
        for (int j = jbeg; j < jend; ++j) IOU2(g4[j], gA[j]);
    }
#undef IOU2

    flg[w][lane]      = (uint8_t)((aF0 >= 0.0f ? 1u : 0u) | (aB0 > 0.0f ? 2u : 0u));
    flg[w][64 + lane] = (uint8_t)((aF1 >= 0.0f ? 1u : 0u) | (aB1 > 0.0f ? 2u : 0u));
    __syncthreads();

    if (t < 128) {
        const uint32_t u = (uint32_t)flg[0][t] | flg[1][t] | flg[2][t] | flg[3][t];
        const int i2 = base + t;
        int cls = (u & 1u) ? 1 : ((u & 2u) ? 2 : 0);
        if (i2 >= N) cls = 0;
        unsigned long long mF = __ballot(cls == 1);
        unsigned long long mB = __ballot(cls == 2);
        if ((t & 63) == 0) {
            ulonglong2 v; v.x = mF; v.y = mB;
            mb2[blockIdx.x * 2 + (t >> 6)] = v;
        }
    }
}

// ---------------- Kernel 2: ordered first-k selection + fg argmax + epilogue ----
// Single block. Counts from mask popcounts; parallel scan; worklist entries
// carry their own prefix (order-independent); ONE thread per work chunk does a
// 16B mask load + ctz bit-scatter; argmax over LDS-staged gt, 32grp x 8 lanes.
__global__ __launch_bounds__(256) void ptl_select_emit(
    const float* __restrict__ all_rois, const float* __restrict__ gt,
    const ulonglong2* __restrict__ mb2,
    int R, int G, int N, int nch,
    float* __restrict__ out)
{
#pragma clang fp contract(off)
    __shared__ int sF[MAXCH], sB[MAXCH];
    __shared__ int tsF[256], tsB[256];
    __shared__ int keep[OUT_ROIS];
    __shared__ int sam[OUT_ROIS];
    __shared__ int nwork;
    __shared__ uint32_t work[256];     // (chunk<<16)|(EFclamp<<8)|EBclamp ; <=128 entries
    __shared__ float4 g4s[256];
    __shared__ float  gAs[256];
    const int t = threadIdx.x;

    if (t < G) {
        const float* p = gt + (size_t)t * 6;
        const float a = p[0], b = p[1], c = p[2], d = p[3];
        g4s[t] = make_float4(a, b, c, d);
        gAs[t] = ((c - a) + 1.0f) * ((d - b) + 1.0f);
    }
    for (int c = t; c < MAXCH; c += 256) {
        if (c < nch) {
            const ulonglong2 v = mb2[c];
            sF[c] = __popcll(v.x); sB[c] = __popcll(v.y);
        } else { sF[c] = 0; sB[c] = 0; }
    }
    if (t < OUT_ROIS) { keep[t] = 0; sam[t] = 0; }   // unfilled slots -> roi 0
    if (t == 0) nwork = 0;
    __syncthreads();

    // per-thread sums over MAXCH/256 chunks, then Hillis-Steele scan
    const int c0 = t * (MAXCH / 256);
    int baseF = 0, baseB = 0;
#pragma unroll
    for (int k = 0; k < MAXCH / 256; ++k) { baseF += sF[c0 + k]; baseB += sB[c0 + k]; }
    tsF[t] = baseF; tsB[t] = baseB;
    __syncthreads();
    for (int d = 1; d < 256; d <<= 1) {
        int vF = (t >= d) ? tsF[t - d] : 0;
        int vB = (t >= d) ? tsB[t - d] : 0;
        __syncthreads();
        tsF[t] += vF; tsB[t] += vB;
        __syncthreads();
    }
    const int tf = tsF[255], tb = tsB[255];
    const int num_fg = tf < FG_MAX ? tf : FG_MAX;
    const int rem = OUT_ROIS - num_fg;
    const int num_bg = tb < rem ? tb : rem;

    // worklist: chunks contributing to first num_fg fg / num_bg bg
    int rF = tsF[t] - baseF, rB = tsB[t] - baseB;
#pragma unroll
    for (int k = 0; k < MAXCH / 256; ++k) {
        const int c = c0 + k;
        const int cf = sF[c], cb = sB[c];
        const bool need = ((cf > 0 && rF < num_fg) || (cb > 0 && rB < num_bg)) && (c < nch);
        if (need) {
            const uint32_t efc = (uint32_t)(rF < 255 ? rF : 255);
            const uint32_t ebc = (uint32_t)(rB < 255 ? rB : 255);
            const int p = atomicAdd(&nwork, 1);
            work[p] = ((uint32_t)c << 16) | (efc << 8) | ebc;
        }
        rF += cf; rB += cb;
    }
    __syncthreads();

    // compaction: one thread per work chunk; 16B mask load + ctz scatter
    const int nw = nwork;
    for (int idx = t; idx < nw; idx += 256) {
        const uint32_t e = work[idx];
        const int c = (int)(e >> 16);
        const ulonglong2 v = mb2[c];
        unsigned long long m = v.x;
        int off = (int)((e >> 8) & 0xFF);
        while (m) {
            const int b = __builtin_ctzll(m);
            m &= m - 1;
            if (off < num_fg) keep[off] = c * 64 + b;
            ++off;
        }
        m = v.y;
        off = (int)(e & 0xFF);
        while (m) {
            const int b = __builtin_ctzll(m);
            m &= m - 1;
            if (off < num_bg) keep[num_fg + off] = c * 64 + b;
            ++off;
        }
    }
    __syncthreads();

    // fg argmax, one pass: 32 groups x 8 lanes over LDS-staged gt; IEEE f32 div;
    // (max, min-index) reduce == numpy first-occurrence argmax.
    {
        const int grp = t >> 3, l8 = t & 7;
        if (grp < num_fg) {
            const int k = keep[grp];
            float x1, y1, x2, y2;
            if (k < R) { const float* p = all_rois + (size_t)k * 5; x1=p[1]; y1=p[2]; x2=p[3]; y2=p[4]; }
            else       { const float* p = gt + (size_t)(k - R) * 6; x1=p[0]; y1=p[1]; x2=p[2]; y2=p[3]; }
            const float A = ((x2 - x1) + 1.0f) * ((y2 - y1) + 1.0f);
            float mv = -1.0f; int mj = 0;
            for (int j = l8; j < G; j += 8) {
                const float4 q = g4s[j];
                const float ga = gAs[j];
                float iw = (fminf(x2, q.z) - fmaxf(x1, q.x)) + 1.0f;
                float ih = (fminf(y2, q.w) - fmaxf(y1, q.y)) + 1.0f;
                iw = fmaxf(iw, 0.0f); ih = fmaxf(ih, 0.0f);
                const float inter = iw * ih;
                const float iou = inter / ((A + ga) - inter);   // IEEE, matches numpy
                if (iou > mv) { mv = iou; mj = j; }
            }
#pragma unroll
            for (int m = 1; m < 8; m <<= 1) {     // xor within aligned 8-groups
                const float ov = __shfl_xor(mv, m);
                const int oj = __shfl_xor(mj, m);
                if (ov > mv || (ov == mv && oj < mj)) { mv = ov; mj = oj; }
            }
            if (l8 == 0) sam[grp] = mj;
        }
    }
    __syncthreads();

    if (t < OUT_ROIS) {
        const int s = t;
        const int k = keep[s];
        const bool isfg = s < num_fg;
        float x1, y1, x2, y2;
        if (k < R) { const float* p = all_rois + (size_t)k * 5; x1=p[1]; y1=p[2]; x2=p[3]; y2=p[4]; }
        else       { const float* p = gt + (size_t)(k - R) * 6; x1=p[0]; y1=p[1]; x2=p[2]; y2=p[3]; }
        const int amax = sam[s];
        const float* g = gt + (size_t)amax * 6;
        const float gx1v = g[0], gy1v = g[1], gx2v = g[2], gy2v = g[3];
        const float label = isfg ? g[4] : 0.0f;
        const float pid = isfg ? g[5] : BG_PID_F;

        float* ro = out + (size_t)s * 5;
        ro[0] = 0.0f; ro[1] = x1; ro[2] = y1; ro[3] = x2; ro[4] = y2;
        out[640 + s] = (float)(int)label;
        out[768 + s] = (float)(int)pid;

        const float ew = (x2 - x1) + 1.0f, eh = (y2 - y1) + 1.0f;
        const float ecx = x1 + 0.5f * ew, ecy = y1 + 0.5f * eh;
        const float gw = (gx2v - gx1v) + 1.0f, gh = (gy2v - gy1v) + 1.0f;
        const float gcx = gx1v + 0.5f * gw, gcy = gy1v + 0.5f * gh;
        float tv[4];
        tv[0] = ((gcx - ecx) / ew) / 0.1f;
        tv[1] = ((gcy - ecy) / eh) / 0.1f;
        tv[2] = logf(gw / ew) / 0.2f;
        tv[3] = logf(gh / eh) / 0.2f;

        const int cls = (int)roundf(label);
        const float on = (label > 0.0f) ? 1.0f : 0.0f;

        float* bt = out + 896  + (size_t)s * 8;
        float* bi = out + 1920 + (size_t)s * 8;
        float* bo = out + 2944 + (size_t)s * 8;
#pragma unroll
        for (int cc = 0; cc < 2; ++cc) {
            const float sel = (cc == cls) ? on : 0.0f;
#pragma unroll
            for (int j = 0; j < 4; ++j) {
                bt[cc * 4 + j] = sel * tv[j];
                bi[cc * 4 + j] = sel;
                bo[cc * 4 + j] = sel;
            }
        }
    }
}

extern "C" void kernel_launch(void* const* d_in, const int* in_sizes, int n_in,
                              void* d_out, int out_size, void* d_ws, size_t ws_size,
                              hipStream_t stream) {
    const float* all_rois = (const float*)d_in[0];
    const float* gt       = (const float*)d_in[1];
    const int R = in_sizes[0] / 5;
    const int G = in_sizes[1] / 6;
    const int N = R + G;
    const int nblk = (N + 127) / 128;  // classify tiles (128 rois each)
    const int nch = (N + 63) / 64;     // 64-roi chunks for selection

    // ws: mb2 ulonglong2[2*nblk] (16B-aligned at ws base)
    ulonglong2* mb2 = (ulonglong2*)d_ws;
    float* out = (float*)d_out;

    ptl_classify<<<nblk, 256, 0, stream>>>(all_rois, gt, R, G, N, mb2);
    ptl_select_emit<<<1, 256, 0, stream>>>(all_rois, gt, mb2, R, G, N, nch, out);
}

// Round 11
// 37.790 us; speedup vs baseline: 1.3799x; 1.0251x over previous
//
#include <hip/hip_runtime.h>
#include <stdint.h>

#define OUT_ROIS 128
#define FG_MAX 32
#define BG_PID_F 5532.0f
#define MAXCH 2304            // 256 threads x 9 chunks; N <= 147456
#define CPT 9                 // chunks per thread in select

// Exact f32 threshold discriminants (no division, no f64):
//  FG: RN32(I/D) >= 0.5f  <=>  I - (0.5-2^-26)*D >= 0   [tie->even lands on 0.5f: inclusive]
//  BG: RN32(I/D) >= 0.1f  <=>  I - (0.1f-2^-28)*D > 0   [tie->even lands on pred(0.1f): strict]

// ---------------- Kernel 1: per-roi fg/bg classification ----------------
// 4-wave block, wave w covers gt-quarter [64w,64w+64), 2 rois/lane.
// gt area recomputed in registers (reference expr tree, bit-identical) --
// LDS traffic is ONE ds_read_b128 per j (gA array eliminated).
__global__ __launch_bounds__(256, 4) void ptl_classify(
    const float* __restrict__ all_rois, const float* __restrict__ gt,
    int R, int G, int N,
    ulonglong2* __restrict__ mb2)
{
#pragma clang fp contract(off)
    __shared__ float4 g4[256];
    __shared__ uint8_t flg[4][128];
    const int t = threadIdx.x;
    const int w = t >> 6, lane = t & 63;

    if (t < G) {
        const float* p = gt + (size_t)t * 6;
        g4[t] = make_float4(p[0], p[1], p[2], p[3]);
    }
    __syncthreads();

    const int base = blockIdx.x * 128;
    float x1a, y1a, x2a, y2a, x1b, y1b, x2b, y2b;
    {
        const int i0 = base + lane;
        if (i0 < N) {
            if (i0 < R) { const float* p = all_rois + (size_t)i0 * 5; x1a=p[1]; y1a=p[2]; x2a=p[3]; y2a=p[4]; }
            else        { const float* p = gt + (size_t)(i0 - R) * 6; x1a=p[0]; y1a=p[1]; x2a=p[2]; y2a=p[3]; }
        } else { x1a=0.0f; y1a=0.0f; x2a=-2.0f; y2a=-2.0f; }
        const int i1 = base + 64 + lane;
        if (i1 < N) {
            if (i1 < R) { const float* p = all_rois + (size_t)i1 * 5; x1b=p[1]; y1b=p[2]; x2b=p[3]; y2b=p[4]; }
            else        { const float* p = gt + (size_t)(i1 - R) * 6; x1b=p[0]; y1b=p[1]; x2b=p[2]; y2b=p[3]; }
        } else { x1b=0.0f; y1b=0.0f; x2b=-2.0f; y2b=-2.0f; }
    }
    const float Aa = ((x2a - x1a) + 1.0f) * ((y2a - y1a) + 1.0f);
    const float Ab = ((x2b - x1b) + 1.0f) * ((y2b - y1b) + 1.0f);

    float aF0 = -1e38f, aB0 = -1e38f, aF1 = -1e38f, aB1 = -1e38f;

#define IOU2(QQ)                                                        \
    do {                                                                \
        const float4 q_ = (QQ);                                         \
        const float ga_ = ((q_.z - q_.x) + 1.0f) * ((q_.w - q_.y) + 1.0f); \
        {   float iw = (fminf(x2a, q_.z) - fmaxf(x1a, q_.x)) + 1.0f;    \
            float ih = (fminf(y2a, q_.w) - fmaxf(y1a, q_.y)) + 1.0f;    \
            iw = fmaxf(iw, 0.0f); ih = fmaxf(ih, 0.0f);                 \
            const float I = iw * ih;                                    \
            const float D = (Aa + ga_) - I;                             \
            const float h  = fmaf(-0.5f, D, I);                         \
            const float gF = fmaf(0x1p-26f, D, h);                      \
            const float h2 = fmaf(-0.1f, D, I);                         \
            const float gB = fmaf(0x1p-28f, D, h2);                     \
            aF0 = fmaxf(aF0, gF); aB0 = fmaxf(aB0, gB); }               \
        {   float iw = (fminf(x2b, q_.z) - fmaxf(x1b, q_.x)) + 1.0f;    \
            float ih = (fminf(y2b, q_.w) - fmaxf(y1b, q_.y)) + 1.0f;    \
            iw = fmaxf(iw, 0.0f); ih = fmaxf(ih, 0.0f);                 \
            const float I = iw * ih;                                    \
            const float D = (Ab + ga_) - I;                             \
            const float h  = fmaf(-0.5f, D, I);                         \
            const float gF = fmaf(0x1p-26f, D, h);                      \
            const float h2 = fmaf(-0.1f, D, I);                         \
            const float gB = fmaf(0x1p-28f, D, h2);                     \
            aF1 = fmaxf(aF1, gF); aB1 = fmaxf(aB1, gB); }               \
    } while (0)

    if (G == 256) {
        const int jbeg = w * 64;
        float4 qb0[8], qb1[8];
#pragma unroll
        for (int uu = 0; uu < 8; ++uu) qb0[uu] = g4[jbeg + uu];
#pragma unroll
        for (int grp = 0; grp < 8; ++grp) {
            if ((grp & 1) == 0) {
                if (grp + 1 < 8) {
#pragma unroll
                    for (int uu = 0; uu < 8; ++uu) qb1[uu] = g4[jbeg + (grp + 1) * 8 + uu];
                }
#pragma unroll
                for (int uu = 0; uu < 8; ++uu) IOU2(qb0[uu]);
            } else {
                if (grp + 1 < 8) {
#pragma unroll
                    for (int uu = 0; uu < 8; ++uu) qb0[uu] = g4[jbeg + (grp + 1) * 8 + uu];
                }
#pragma unroll
                for (int uu = 0; uu < 8; ++uu) IOU2(qb1[uu]);
            }
        }
    } else {
        const int jbeg = (G * w) >> 2, jend = (G * (w + 1)) >> 2;
        for (int j = jbeg; j < jend; ++j) IOU2(g4[j]);
    }
#undef IOU2

    flg[w][lane]      = (uint8_t)((aF0 >= 0.0f ? 1u : 0u) | (aB0 > 0.0f ? 2u : 0u));
    flg[w][64 + lane] = (uint8_t)((aF1 >= 0.0f ? 1u : 0u) | (aB1 > 0.0f ? 2u : 0u));
    __syncthreads();

    if (t < 128) {
        const uint32_t u = (uint32_t)flg[0][t] | flg[1][t] | flg[2][t] | flg[3][t];
        const int i2 = base + t;
        int cls = (u & 1u) ? 1 : ((u & 2u) ? 2 : 0);
        if (i2 >= N) cls = 0;
        unsigned long long mF = __ballot(cls == 1);
        unsigned long long mB = __ballot(cls == 2);
        if ((t & 63) == 0) {
            ulonglong2 v; v.x = mF; v.y = mB;
            mb2[blockIdx.x * 2 + (t >> 6)] = v;
        }
    }
}

// ---------------- Kernel 2: ordered first-k selection + fg argmax + epilogue ----
// Single block, 256 threads, 4 barriers. Counts live in registers (9 chunks
// per thread); wave shfl-scans + one cross-wave combine replace the LDS scan.
__global__ __launch_bounds__(256) void ptl_select_emit(
    const float* __restrict__ all_rois, const float* __restrict__ gt,
    const ulonglong2* __restrict__ mb2,
    int R, int G, int N, int nch,
    float* __restrict__ out)
{
#pragma clang fp contract(off)
    __shared__ float4 g4s[256];
    __shared__ float  gAs[256];
    __shared__ int keep[OUT_ROIS];
    __shared__ int sam[OUT_ROIS];
    __shared__ int wtF[4], wtB[4];
    __shared__ int nwork;
    __shared__ uint32_t work[256];     // (chunk<<16)|(EFclamp<<8)|EBclamp ; <=160 entries
    const int t = threadIdx.x;
    const int w = t >> 6, lane = t & 63;

    if (t < G) {
        const float* p = gt + (size_t)t * 6;
        const float a = p[0], b = p[1], c = p[2], d = p[3];
        g4s[t] = make_float4(a, b, c, d);
        gAs[t] = ((c - a) + 1.0f) * ((d - b) + 1.0f);
    }
    if (t < OUT_ROIS) { keep[t] = 0; sam[t] = 0; }   // unfilled slots -> roi 0
    if (t == 0) nwork = 0;

    // per-thread counts over 9 contiguous chunks (registers, static indices)
    int cFr[CPT], cBr[CPT];
    int sumF = 0, sumB = 0;
    const int c0 = t * CPT;
#pragma unroll
    for (int k = 0; k < CPT; ++k) {
        int f = 0, b = 0;
        const int c = c0 + k;
        if (c < nch) { const ulonglong2 v = mb2[c]; f = __popcll(v.x); b = __popcll(v.y); }
        cFr[k] = f; cBr[k] = b; sumF += f; sumB += b;
    }
    // wave inclusive scan (no barriers)
    int iF = sumF, iB = sumB;
#pragma unroll
    for (int d = 1; d < 64; d <<= 1) {
        const int vF = __shfl_up(iF, d);
        const int vB = __shfl_up(iB, d);
        if (lane >= d) { iF += vF; iB += vB; }
    }
    if (lane == 63) { wtF[w] = iF; wtB[w] = iB; }
    __syncthreads();

    int preF = 0, preB = 0;
    for (int ww = 0; ww < w; ++ww) { preF += wtF[ww]; preB += wtB[ww]; }
    const int tf = wtF[0] + wtF[1] + wtF[2] + wtF[3];
    const int tb = wtB[0] + wtB[1] + wtB[2] + wtB[3];
    const int num_fg = tf < FG_MAX ? tf : FG_MAX;
    const int rem = OUT_ROIS - num_fg;
    const int num_bg = tb < rem ? tb : rem;

    // worklist: chunks contributing to first num_fg fg / num_bg bg
    int rF = preF + iF - sumF;         // exclusive prefix at this thread's chunk 0
    int rB = preB + iB - sumB;
#pragma unroll
    for (int k = 0; k < CPT; ++k) {
        const int c = c0 + k;
        const int cf = cFr[k], cb = cBr[k];
        const bool need = ((cf > 0 && rF < num_fg) || (cb > 0 && rB < num_bg)) && (c < nch);
        if (need) {
            const uint32_t efc = (uint32_t)(rF < 255 ? rF : 255);
            const uint32_t ebc = (uint32_t)(rB < 255 ? rB : 255);
            const int p = atomicAdd(&nwork, 1);
            work[p] = ((uint32_t)c << 16) | (efc << 8) | ebc;
        }
        rF += cf; rB += cb;
    }
    __syncthreads();

    // compaction: one thread per work chunk; 16B mask load + ctz scatter
    const int nw = nwork;
    for (int idx = t; idx < nw; idx += 256) {
        const uint32_t e = work[idx];
        const int c = (int)(e >> 16);
        const ulonglong2 v = mb2[c];
        unsigned long long m = v.x;
        int off = (int)((e >> 8) & 0xFF);
        while (m) {
            const int b = __builtin_ctzll(m);
            m &= m - 1;
            if (off < num_fg) keep[off] = c * 64 + b;
            ++off;
        }
        m = v.y;
        off = (int)(e & 0xFF);
        while (m) {
            const int b = __builtin_ctzll(m);
            m &= m - 1;
            if (off < num_bg) keep[num_fg + off] = c * 64 + b;
            ++off;
        }
    }
    __syncthreads();

    // fg argmax, one pass: 32 groups x 8 lanes over LDS-staged gt; IEEE f32 div;
    // (max, min-index) reduce == numpy first-occurrence argmax.
    {
        const int grp = t >> 3, l8 = t & 7;
        if (grp < num_fg) {
            const int k = keep[grp];
            float x1, y1, x2, y2;
            if (k < R) { const float* p = all_rois + (size_t)k * 5; x1=p[1]; y1=p[2]; x2=p[3]; y2=p[4]; }
            else       { const float* p = gt + (size_t)(k - R) * 6; x1=p[0]; y1=p[1]; x2=p[2]; y2=p[3]; }
            const float A = ((x2 - x1) + 1.0f) * ((y2 - y1) + 1.0f);
            float mv = -1.0f; int mj = 0;
            for (int j = l8; j < G; j += 8) {
                const float4 q = g4s[j];
                const float ga = gAs[j];
                float iw = (fminf(x2, q.z) - fmaxf(x1, q.x)) + 1.0f;
                float ih = (fminf(y2, q.w) - fmaxf(y1, q.y)) + 1.0f;
                iw = fmaxf(iw, 0.0f); ih = fmaxf(ih, 0.0f);
                const float inter = iw * ih;
                const float iou = inter / ((A + ga) - inter);   // IEEE, matches numpy
                if (iou > mv) { mv = iou; mj = j; }
            }
#pragma unroll
            for (int m = 1; m < 8; m <<= 1) {     // xor within aligned 8-groups
                const float ov = __shfl_xor(mv, m);
                const int oj = __shfl_xor(mj, m);
                if (ov > mv || (ov == mv && oj < mj)) { mv = ov; mj = oj; }
            }
            if (l8 == 0) sam[grp] = mj;
        }
    }
    __syncthreads();

    if (t < OUT_ROIS) {
        const int s = t;
        const int k = keep[s];
        const bool isfg = s < num_fg;
        float x1, y1, x2, y2;
        if (k < R) { const float* p = all_rois + (size_t)k * 5; x1=p[1]; y1=p[2]; x2=p[3]; y2=p[4]; }
        else       { const float* p = gt + (size_t)(k - R) * 6; x1=p[0]; y1=p[1]; x2=p[2]; y2=p[3]; }
        const int amax = sam[s];
        const float* g = gt + (size_t)amax * 6;
        const float gx1v = g[0], gy1v = g[1], gx2v = g[2], gy2v = g[3];
        const float label = isfg ? g[4] : 0.0f;
        const float pid = isfg ? g[5] : BG_PID_F;

        float* ro = out + (size_t)s * 5;
        ro[0] = 0.0f; ro[1] = x1; ro[2] = y1; ro[3] = x2; ro[4] = y2;
        out[640 + s] = (float)(int)label;
        out[768 + s] = (float)(int)pid;

        const float ew = (x2 - x1) + 1.0f, eh = (y2 - y1) + 1.0f;
        const float ecx = x1 + 0.5f * ew, ecy = y1 + 0.5f * eh;
        const float gw = (gx2v - gx1v) + 1.0f, gh = (gy2v - gy1v) + 1.0f;
        const float gcx = gx1v + 0.5f * gw, gcy = gy1v + 0.5f * gh;
        float tv[4];
        tv[0] = ((gcx - ecx) / ew) / 0.1f;
        tv[1] = ((gcy - ecy) / eh) / 0.1f;
        tv[2] = logf(gw / ew) / 0.2f;
        tv[3] = logf(gh / eh) / 0.2f;

        const int cls = (int)roundf(label);
        const float on = (label > 0.0f) ? 1.0f : 0.0f;

        float* bt = out + 896  + (size_t)s * 8;
        float* bi = out + 1920 + (size_t)s * 8;
        float* bo = out + 2944 + (size_t)s * 8;
#pragma unroll
        for (int cc = 0; cc < 2; ++cc) {
            const float sel = (cc == cls) ? on : 0.0f;
#pragma unroll
            for (int j = 0; j < 4; ++j) {
                bt[cc * 4 + j] = sel * tv[j];
                bi[cc * 4 + j] = sel;
                bo[cc * 4 + j] = sel;
            }
        }
    }
}

extern "C" void kernel_launch(void* const* d_in, const int* in_sizes, int n_in,
                              void* d_out, int out_size, void* d_ws, size_t ws_size,
                              hipStream_t stream) {
    const float* all_rois = (const float*)d_in[0];
    const float* gt       = (const float*)d_in[1];
    const int R = in_sizes[0] / 5;
    const int G = in_sizes[1] / 6;
    const int N = R + G;
    const int nblk = (N + 127) / 128;  // classify tiles (128 rois each)
    const int nch = (N + 63) / 64;     // 64-roi chunks for selection

    // ws: mb2 ulonglong2[2*nblk] (16B-aligned at ws base)
    ulonglong2* mb2 = (ulonglong2*)d_ws;
    float* out = (float*)d_out;

    ptl_classify<<<nblk, 256, 0, stream>>>(all_rois, gt, R, G, N, mb2);
    ptl_select_emit<<<1, 256, 0, stream>>>(all_rois, gt, mb2, R, G, N, nch, out);
}